// Round 11
// baseline (209.919 us; speedup 1.0000x reference)
//
#include <hip/hip_runtime.h>

#define N_NODES 100000
#define N_EDGES 1600000
#define F_IN    128
#define HID     128
#define F_OUT   64

#define NBUCK   196        // buckets of 512 nodes: dst>>9
#define NCHB    256        // chunk blocks for bucket hist/scatter
#define CHUNK_E (N_EDGES / NCHB)   // 6250 exactly
#define GHN     (NBUCK * NCHB)     // 50176 ghist entries
#define SCAN_BLKS (GHN / 256)      // 196 (exact)

#define WC_BLKS ((HID * F_IN + F_OUT * HID + 255) / 256)  // 96
#define CSR_LDS 9216       // per-bucket edge cache (E[bucket]=8163, +11 sigma)

typedef __attribute__((ext_vector_type(8))) short bf16x8;
typedef __attribute__((ext_vector_type(4))) float f32x4;

// ---------------- bf16 helpers ----------------

__device__ __forceinline__ unsigned int bf16rn(float f) {
    unsigned int u = __float_as_uint(f);
    return (u + 0x7fffu + ((u >> 16) & 1u)) >> 16;
}
__device__ __forceinline__ float bf16tof(unsigned short h) {
    return __uint_as_float(((unsigned int)h) << 16);
}

// ---------------- pre: weight transpose + bucket histogram ----------------

__global__ __launch_bounds__(256) void k_pre0(
        const float* __restrict__ W1, const float* __restrict__ W2,
        unsigned short* __restrict__ w1t, unsigned short* __restrict__ w2t,
        const int* __restrict__ dst, int* __restrict__ ghist) {
    __shared__ int bins[NBUCK];
    const int blk = blockIdx.x;
    const int t = threadIdx.x;
    if (blk < WC_BLKS) {
        int i = blk * 256 + t;
        if (i < HID * F_IN) {
            int n = i >> 7, k = i & 127;
            w1t[i] = (unsigned short)bf16rn(W1[k * HID + n]);
        }
        int j = i - HID * F_IN;
        if (j >= 0 && j < F_OUT * HID) {
            int n = j >> 7, k = j & 127;
            w2t[j] = (unsigned short)bf16rn(W2[k * F_OUT + n]);
        }
    } else {
        int cb = blk - WC_BLKS;
        for (int j = t; j < NBUCK; j += 256) bins[j] = 0;
        __syncthreads();
        const int base = cb * CHUNK_E;
        for (int i = t; i < CHUNK_E; i += 256)
            atomicAdd(&bins[dst[base + i] >> 9], 1);
        __syncthreads();
        for (int j = t; j < NBUCK; j += 256)
            ghist[j * NCHB + cb] = bins[j];       // bucket-major
    }
}

// ---------------- single-kernel exclusive scan: ghist -> ghs ----------------
// Each block redundantly stream-sums its prefix (max 200KB, coalesced), then
// LDS-scans its own 256-chunk. Separate output buffer avoids in-place race.

__global__ __launch_bounds__(256) void k_scan(const int* __restrict__ ghist,
                                              int* __restrict__ ghs) {
    __shared__ int red[256];
    const int t = threadIdx.x;
    const int b = blockIdx.x;

    int s = 0;
    for (int i = t; i < b * 256; i += 256) s += ghist[i];
    red[t] = s;
    __syncthreads();
    for (int off = 128; off > 0; off >>= 1) {
        if (t < off) red[t] += red[t + off];
        __syncthreads();
    }
    const int base = red[0];
    __syncthreads();

    int v = ghist[b * 256 + t];
    red[t] = v;
    __syncthreads();
    for (int off = 1; off < 256; off <<= 1) {
        int u = (t >= off) ? red[t - off] : 0;
        __syncthreads();
        red[t] += u;
        __syncthreads();
    }
    ghs[b * 256 + t] = base + red[t] - v;         // exclusive
}

// ---------------- bucket scatter: LDS cursors, dlocal packed into bits 17..25 ----------------

__global__ __launch_bounds__(256) void k_bscatter(const int* __restrict__ src,
                                                  const int* __restrict__ dst,
                                                  const float* __restrict__ w,
                                                  const int* __restrict__ ghs,  // scanned
                                                  int2* __restrict__ spw) {
    __shared__ int cur[NBUCK];
    const int t = threadIdx.x;
    const int blk = blockIdx.x;
    for (int j = t; j < NBUCK; j += 256) cur[j] = ghs[j * NCHB + blk];
    __syncthreads();
    const int base = blk * CHUNK_E;
    for (int i = t; i < CHUNK_E; i += 256) {
        int e = base + i;
        int d = dst[e];
        int b = d >> 9;
        int pos = atomicAdd(&cur[b], 1);
        int2 p;
        p.x = src[e] | ((d & 511) << 17);     // src < 2^17
        p.y = __float_as_int(w[e]);
        spw[pos] = p;
    }
}

// ---------------- per-bucket CSR finalize: row_ptr, dinv, pairs ----------------
// Bucket's spw slice cached in LDS (block-uniform fallback to global if oversized).

__global__ __launch_bounds__(512) void k_csr(const int2* __restrict__ spw,
                                             const int* __restrict__ ghs,   // scanned
                                             int* __restrict__ row_ptr,
                                             float* __restrict__ dinv,
                                             int2* __restrict__ pairs) {
    __shared__ int   scnt[512];
    __shared__ float swsum[512];
    __shared__ int   sexcl[512];
    __shared__ int2  sspw[CSR_LDS];
    const int t = threadIdx.x;
    const int b = blockIdx.x;
    const int bstart = ghs[b * NCHB];
    const int bend   = (b == NBUCK - 1) ? N_EDGES : ghs[(b + 1) * NCHB];
    const int ne = bend - bstart;
    const bool inlds = (ne <= CSR_LDS);           // block-uniform

    scnt[t] = 0; swsum[t] = 0.0f;
    if (inlds)
        for (int i = t; i < ne; i += 512) sspw[i] = spw[bstart + i];
    __syncthreads();

    for (int i = t; i < ne; i += 512) {
        int2 pe = inlds ? sspw[i] : spw[bstart + i];
        int dl = pe.x >> 17;
        atomicAdd(&scnt[dl], 1);
        atomicAdd(&swsum[dl], __int_as_float(pe.y));
    }
    __syncthreads();

    sexcl[t] = scnt[t];
    __syncthreads();
    for (int off = 1; off < 512; off <<= 1) {
        int u = (t >= off) ? sexcl[t - off] : 0;
        __syncthreads();
        sexcl[t] += u;
        __syncthreads();
    }
    int excl = sexcl[t] - scnt[t];

    int node = b * 512 + t;
    if (node < N_NODES) {
        row_ptr[node] = bstart + excl;
        dinv[node] = rsqrtf(1.0f + swsum[t]);
    }
    if (b == NBUCK - 1 && t == 0) row_ptr[N_NODES] = N_EDGES;

    sexcl[t] = excl;
    __syncthreads();
    scnt[t] = 0;
    __syncthreads();

    for (int i = t; i < ne; i += 512) {
        int2 pe = inlds ? sspw[i] : spw[bstart + i];
        int dl = pe.x >> 17;
        int r = atomicAdd(&scnt[dl], 1);
        int2 q;
        q.x = pe.x & 0x1FFFF;
        q.y = pe.y;
        pairs[bstart + sexcl[dl] + r] = q;
    }
}

// ---------------- xhs = bf16(dinv[n] * x[n]) — dinv-prescaled features ----------------

__global__ __launch_bounds__(256) void k_xhs(const float* __restrict__ x,
                                             const float* __restrict__ dinv,
                                             unsigned short* __restrict__ xhs) {
    int i = blockIdx.x * 256 + threadIdx.x;       // over N*16 (8 floats each)
    if (i < N_NODES * 16) {
        float dn = dinv[i >> 4];
        float4 a = ((const float4*)x)[2 * i];
        float4 b = ((const float4*)x)[2 * i + 1];
        uint4 r;
        r.x = bf16rn(dn * a.x) | (bf16rn(dn * a.y) << 16);
        r.y = bf16rn(dn * a.z) | (bf16rn(dn * a.w) << 16);
        r.z = bf16rn(dn * b.x) | (bf16rn(dn * b.y) << 16);
        r.w = bf16rn(dn * b.z) | (bf16rn(dn * b.w) << 16);
        ((uint4*)xhs)[i] = r;
    }
}

// ---------------- gather-aggregate: axh[n] = bf16( dn * (xhs[n] + sum_e w*xhs[src]) ) ----------------
// No dinv in the inner loop: 2 VMEM/edge (pairs stream + xhs row gather).

__global__ __launch_bounds__(256) void k_gather(const int2* __restrict__ pairs,
                                                const int* __restrict__ row_ptr,
                                                const float* __restrict__ dinv,
                                                const unsigned short* __restrict__ xhs,
                                                unsigned short* __restrict__ axh) {
    int t = blockIdx.x * 256 + threadIdx.x;
    int n = t >> 5;
    int lane = t & 31;
    if (n >= N_NODES) return;

    const ushort4* xs4 = (const ushort4*)xhs;
    float dn = dinv[n];
    ushort4 sv = xs4[n * 32 + lane];              // self term = xhs[n]
    float4 acc;
    acc.x = bf16tof(sv.x);
    acc.y = bf16tof(sv.y);
    acc.z = bf16tof(sv.z);
    acc.w = bf16tof(sv.w);

    int beg = row_ptr[n];
    int end = row_ptr[n + 1];
    int e = beg;
    for (; e + 3 < end; e += 4) {                 // 4 independent gathers in flight
        int2 p0 = pairs[e];
        int2 p1 = pairs[e + 1];
        int2 p2 = pairs[e + 2];
        int2 p3 = pairs[e + 3];
        float w0 = __int_as_float(p0.y);
        float w1 = __int_as_float(p1.y);
        float w2 = __int_as_float(p2.y);
        float w3 = __int_as_float(p3.y);
        ushort4 v0 = xs4[p0.x * 32 + lane];
        ushort4 v1 = xs4[p1.x * 32 + lane];
        ushort4 v2 = xs4[p2.x * 32 + lane];
        ushort4 v3 = xs4[p3.x * 32 + lane];
        acc.x += w0 * bf16tof(v0.x); acc.y += w0 * bf16tof(v0.y);
        acc.z += w0 * bf16tof(v0.z); acc.w += w0 * bf16tof(v0.w);
        acc.x += w1 * bf16tof(v1.x); acc.y += w1 * bf16tof(v1.y);
        acc.z += w1 * bf16tof(v1.z); acc.w += w1 * bf16tof(v1.w);
        acc.x += w2 * bf16tof(v2.x); acc.y += w2 * bf16tof(v2.y);
        acc.z += w2 * bf16tof(v2.z); acc.w += w2 * bf16tof(v2.w);
        acc.x += w3 * bf16tof(v3.x); acc.y += w3 * bf16tof(v3.y);
        acc.z += w3 * bf16tof(v3.z); acc.w += w3 * bf16tof(v3.w);
    }
    for (; e < end; ++e) {
        int2 p = pairs[e];
        float w = __int_as_float(p.y);
        ushort4 v = xs4[p.x * 32 + lane];
        acc.x += w * bf16tof(v.x); acc.y += w * bf16tof(v.y);
        acc.z += w * bf16tof(v.z); acc.w += w * bf16tof(v.w);
    }
    acc.x *= dn; acc.y *= dn; acc.z *= dn; acc.w *= dn;
    uint2 r;
    r.x = bf16rn(acc.x) | (bf16rn(acc.y) << 16);
    r.y = bf16rn(acc.z) | (bf16rn(acc.w) << 16);
    ((uint2*)axh)[n * 32 + lane] = r;
}

// ---------------- MFMA MLP: out = relu(axh@W1 + b1) @ W2 + b2 ----------------
// 4 waves/block, 16 rows/wave. 16x16x32 bf16 MFMA, fp32 accum.
// C/D layout (m89-verified): col = lane&15, row = (lane>>4)*4 + reg.
// A/B frag: row(A)/col(B) = lane&15, k = (lane>>4)*8 + i (contiguous 16B).

__global__ __launch_bounds__(256) void k_mlp(
        const unsigned short* __restrict__ axh,   // [N][128] bf16
        const unsigned short* __restrict__ w1t,   // [128][128] bf16, w1t[n][k]
        const float* __restrict__ b1,
        const unsigned short* __restrict__ w2t,   // [64][128] bf16, w2t[n][k]
        const float* __restrict__ b2,
        float* __restrict__ out) {
    __shared__ unsigned short hbuf[4][16][128];   // per-wave h tile, XOR-swizzled

    const int wid  = threadIdx.x >> 6;
    const int lane = threadIdx.x & 63;
    const int r = lane & 15;
    const int g = lane >> 4;

    const int row0 = (blockIdx.x * 4 + wid) * 16;
    const bool valid = (row0 + 16 <= N_NODES);    // N%16==0: waves all-or-nothing
    const int row0s = valid ? row0 : 0;

    bf16x8 a[4];
    const unsigned short* arow = axh + (size_t)(row0s + r) * HID + g * 8;
    #pragma unroll
    for (int kt = 0; kt < 4; ++kt)
        a[kt] = *(const bf16x8*)(arow + kt * 32);

    const int swr = (r & 7) << 3;

    #pragma unroll
    for (int nt = 0; nt < 8; ++nt) {
        f32x4 acc = {0.f, 0.f, 0.f, 0.f};
        const unsigned short* bcol = w1t + (nt * 16 + r) * HID + g * 8;
        #pragma unroll
        for (int kt = 0; kt < 4; ++kt) {
            bf16x8 b = *(const bf16x8*)(bcol + kt * 32);
            acc = __builtin_amdgcn_mfma_f32_16x16x32_bf16(a[kt], b, acc, 0, 0, 0);
        }
        float bias = b1[nt * 16 + r];
        #pragma unroll
        for (int q = 0; q < 4; ++q) {
            int row = g * 4 + q;
            float v = fmaxf(acc[q] + bias, 0.0f);
            hbuf[wid][row][(nt * 16 + r) ^ ((row & 7) << 3)] = (unsigned short)bf16rn(v);
        }
    }
    __syncthreads();   // all waves reach this (no early returns)

    bf16x8 a2[4];
    #pragma unroll
    for (int kt = 0; kt < 4; ++kt)
        a2[kt] = *(const bf16x8*)(&hbuf[wid][r][(kt * 32 + g * 8) ^ swr]);

    #pragma unroll
    for (int nt = 0; nt < 4; ++nt) {
        f32x4 acc = {0.f, 0.f, 0.f, 0.f};
        const unsigned short* bcol = w2t + (nt * 16 + r) * HID + g * 8;
        #pragma unroll
        for (int kt = 0; kt < 4; ++kt) {
            bf16x8 b = *(const bf16x8*)(bcol + kt * 32);
            acc = __builtin_amdgcn_mfma_f32_16x16x32_bf16(a2[kt], b, acc, 0, 0, 0);
        }
        if (valid) {
            float bias = b2[nt * 16 + r];
            #pragma unroll
            for (int q = 0; q < 4; ++q)
                out[(size_t)(row0 + g * 4 + q) * F_OUT + nt * 16 + r] = acc[q] + bias;
        }
    }
}

// ---------------- launch ----------------

extern "C" void kernel_launch(void* const* d_in, const int* in_sizes, int n_in,
                              void* d_out, int out_size, void* d_ws, size_t ws_size,
                              hipStream_t stream) {
    const float* x  = (const float*)d_in[0];
    const int*   ei = (const int*)d_in[1];
    const float* ew = (const float*)d_in[2];
    const float* W1 = (const float*)d_in[3];
    const float* b1 = (const float*)d_in[4];
    const float* W2 = (const float*)d_in[5];
    const float* b2 = (const float*)d_in[6];
    float* out = (float*)d_out;

    const int* src = ei;
    const int* dst = ei + N_EDGES;

    // workspace layout — explicit 16B-aligned carve-out.
    // NOTE: axh aliases spw (spw dead after k_csr; axh written after, in k_gather).
    char* base = (char*)d_ws;
    auto alloc16 = [&](size_t bytes) { char* p = base; base += (bytes + 15) & ~(size_t)15; return p; };

    float*          dinv    = (float*)         alloc16(N_NODES * 4);
    unsigned short* xhs     = (unsigned short*)alloc16((size_t)N_NODES * F_IN * 2);
    int*            row_ptr = (int*)           alloc16((N_NODES + 1) * 4);
    int*            ghist   = (int*)           alloc16(GHN * 4);
    int*            ghs     = (int*)           alloc16(GHN * 4);
    int2*           pairs   = (int2*)          alloc16((size_t)N_EDGES * 8);
    char*           big     =                  alloc16((size_t)N_NODES * HID * 2);  // 25.6MB >= E*8
    unsigned short* w1t     = (unsigned short*)alloc16(HID * F_IN * 2);
    unsigned short* w2t     = (unsigned short*)alloc16(F_OUT * HID * 2);

    int2*           spw     = (int2*)big;              // live: k_bscatter -> k_csr
    unsigned short* axh     = (unsigned short*)big;    // live: k_gather -> k_mlp

    k_pre0<<<WC_BLKS + NCHB, 256, 0, stream>>>(W1, W2, w1t, w2t, dst, ghist);
    k_scan<<<SCAN_BLKS, 256, 0, stream>>>(ghist, ghs);
    k_bscatter<<<NCHB, 256, 0, stream>>>(src, dst, ew, ghs, spw);
    k_csr<<<NBUCK, 512, 0, stream>>>(spw, ghs, row_ptr, dinv, pairs);
    k_xhs<<<(N_NODES * 16 + 255) / 256, 256, 0, stream>>>(x, dinv, xhs);
    k_gather<<<(N_NODES * 32 + 255) / 256, 256, 0, stream>>>(pairs, row_ptr, dinv, xhs, axh);
    k_mlp<<<(N_NODES / 16 + 3) / 4, 256, 0, stream>>>(axh, w1t, b1, w2t, b2, out);
}

// Round 12
// 206.091 us; speedup vs baseline: 1.0186x; 1.0186x over previous
//
#include <hip/hip_runtime.h>

#define N_NODES 100000
#define N_EDGES 1600000
#define F_IN    128
#define HID     128
#define F_OUT   64

#define NBUCK   196        // buckets of 512 nodes: dst>>9
#define NCHB    256        // chunk blocks for bucket hist/scatter
#define CHUNK_E (N_EDGES / NCHB)   // 6250 exactly
#define GHN     (NBUCK * NCHB)     // 50176 ghist entries
#define SCAN_BLKS (GHN / 256)      // 196 (exact)

#define WC_BLKS ((HID * F_IN + F_OUT * HID + 255) / 256)  // 96

typedef __attribute__((ext_vector_type(8))) short bf16x8;
typedef __attribute__((ext_vector_type(8))) unsigned short u16x8;
typedef __attribute__((ext_vector_type(4))) float f32x4;

// ---------------- bf16 helpers ----------------

__device__ __forceinline__ unsigned int bf16rn(float f) {
    unsigned int u = __float_as_uint(f);
    return (u + 0x7fffu + ((u >> 16) & 1u)) >> 16;
}
__device__ __forceinline__ float bf16tof(unsigned short h) {
    return __uint_as_float(((unsigned int)h) << 16);
}

// ---------------- pre: weight transpose + bucket histogram ----------------

__global__ __launch_bounds__(256) void k_pre0(
        const float* __restrict__ W1, const float* __restrict__ W2,
        unsigned short* __restrict__ w1t, unsigned short* __restrict__ w2t,
        const int* __restrict__ dst, int* __restrict__ ghist) {
    __shared__ int bins[NBUCK];
    const int blk = blockIdx.x;
    const int t = threadIdx.x;
    if (blk < WC_BLKS) {
        int i = blk * 256 + t;
        if (i < HID * F_IN) {
            int n = i >> 7, k = i & 127;
            w1t[i] = (unsigned short)bf16rn(W1[k * HID + n]);
        }
        int j = i - HID * F_IN;
        if (j >= 0 && j < F_OUT * HID) {
            int n = j >> 7, k = j & 127;
            w2t[j] = (unsigned short)bf16rn(W2[k * F_OUT + n]);
        }
    } else {
        int cb = blk - WC_BLKS;
        for (int j = t; j < NBUCK; j += 256) bins[j] = 0;
        __syncthreads();
        const int base = cb * CHUNK_E;
        for (int i = t; i < CHUNK_E; i += 256)
            atomicAdd(&bins[dst[base + i] >> 9], 1);
        __syncthreads();
        for (int j = t; j < NBUCK; j += 256)
            ghist[j * NCHB + cb] = bins[j];       // bucket-major
    }
}

// ---------------- single-kernel exclusive scan: ghist -> ghs ----------------

__global__ __launch_bounds__(256) void k_scan(const int* __restrict__ ghist,
                                              int* __restrict__ ghs) {
    __shared__ int red[256];
    const int t = threadIdx.x;
    const int b = blockIdx.x;

    int s = 0;
    for (int i = t; i < b * 256; i += 256) s += ghist[i];
    red[t] = s;
    __syncthreads();
    for (int off = 128; off > 0; off >>= 1) {
        if (t < off) red[t] += red[t + off];
        __syncthreads();
    }
    const int base = red[0];
    __syncthreads();

    int v = ghist[b * 256 + t];
    red[t] = v;
    __syncthreads();
    for (int off = 1; off < 256; off <<= 1) {
        int u = (t >= off) ? red[t - off] : 0;
        __syncthreads();
        red[t] += u;
        __syncthreads();
    }
    ghs[b * 256 + t] = base + red[t] - v;         // exclusive
}

// ---------------- bucket scatter: LDS cursors, dlocal packed into bits 17..25 ----------------

__global__ __launch_bounds__(256) void k_bscatter(const int* __restrict__ src,
                                                  const int* __restrict__ dst,
                                                  const float* __restrict__ w,
                                                  const int* __restrict__ ghs,  // scanned
                                                  int2* __restrict__ spw) {
    __shared__ int cur[NBUCK];
    const int t = threadIdx.x;
    const int blk = blockIdx.x;
    for (int j = t; j < NBUCK; j += 256) cur[j] = ghs[j * NCHB + blk];
    __syncthreads();
    const int base = blk * CHUNK_E;
    for (int i = t; i < CHUNK_E; i += 256) {
        int e = base + i;
        int d = dst[e];
        int b = d >> 9;
        int pos = atomicAdd(&cur[b], 1);
        int2 p;
        p.x = src[e] | ((d & 511) << 17);     // src < 2^17
        p.y = __float_as_int(w[e]);
        spw[pos] = p;
    }
}

// ---------------- per-bucket CSR finalize + fused xhs streaming ----------------
// row_ptr, dinv, pairs; then xhs[n] = bf16(dinv[n]*x[n]) for this bucket's 512 nodes.

__global__ __launch_bounds__(512) void k_csr(const int2* __restrict__ spw,
                                             const int* __restrict__ ghs,   // scanned
                                             const float* __restrict__ x,
                                             int* __restrict__ row_ptr,
                                             float* __restrict__ dinv,
                                             int2* __restrict__ pairs,
                                             unsigned short* __restrict__ xhs) {
    __shared__ int   scnt[512];
    __shared__ float swsum[512];
    __shared__ int   sexcl[512];
    __shared__ float sdinv[512];
    const int t = threadIdx.x;
    const int b = blockIdx.x;
    const int bstart = ghs[b * NCHB];
    const int bend   = (b == NBUCK - 1) ? N_EDGES : ghs[(b + 1) * NCHB];
    const int ne = bend - bstart;

    scnt[t] = 0; swsum[t] = 0.0f;
    __syncthreads();
    for (int i = t; i < ne; i += 512) {
        int2 pe = spw[bstart + i];
        int dl = pe.x >> 17;
        atomicAdd(&scnt[dl], 1);
        atomicAdd(&swsum[dl], __int_as_float(pe.y));
    }
    __syncthreads();

    sexcl[t] = scnt[t];
    __syncthreads();
    for (int off = 1; off < 512; off <<= 1) {
        int u = (t >= off) ? sexcl[t - off] : 0;
        __syncthreads();
        sexcl[t] += u;
        __syncthreads();
    }
    int excl = sexcl[t] - scnt[t];

    const int node = b * 512 + t;
    float dn = rsqrtf(1.0f + swsum[t]);
    sdinv[t] = dn;
    if (node < N_NODES) {
        row_ptr[node] = bstart + excl;
        dinv[node] = dn;
    }
    if (b == NBUCK - 1 && t == 0) row_ptr[N_NODES] = N_EDGES;

    sexcl[t] = excl;
    __syncthreads();
    scnt[t] = 0;
    __syncthreads();

    // scatter pass (reads L2-hot spw)
    for (int i = t; i < ne; i += 512) {
        int2 pe = spw[bstart + i];
        int dl = pe.x >> 17;
        int r = atomicAdd(&scnt[dl], 1);
        int2 q;
        q.x = pe.x & 0x1FFFF;
        q.y = pe.y;
        pairs[bstart + sexcl[dl] + r] = q;
    }

    // fused xhs streaming for this bucket's nodes (independent of scatter pass)
    const int nbase = b * 512;
    for (int idx = t; idx < 512 * 32; idx += 512) {   // float4 granularity
        int row = idx >> 5, c4 = idx & 31;
        int n = nbase + row;
        if (n < N_NODES) {
            float d = sdinv[row];
            float4 a = ((const float4*)x)[n * 32 + c4];
            uint2 r;
            r.x = bf16rn(d * a.x) | (bf16rn(d * a.y) << 16);
            r.y = bf16rn(d * a.z) | (bf16rn(d * a.w) << 16);
            ((uint2*)xhs)[n * 32 + c4] = r;
        }
    }
}

// ---------------- gather-aggregate: 16 lanes/node, 16B loads ----------------
// axh[n] = bf16( dn * (xhs[n] + sum_e w*xhs[src]) ) ; 2 VMEM/edge, dwordx4 width.

__global__ __launch_bounds__(256) void k_gather(const int2* __restrict__ pairs,
                                                const int* __restrict__ row_ptr,
                                                const float* __restrict__ dinv,
                                                const unsigned short* __restrict__ xhs,
                                                unsigned short* __restrict__ axh) {
    int t = blockIdx.x * 256 + threadIdx.x;
    int n = t >> 4;                                // 16 lanes per node
    int lane = t & 15;                             // handles 8 bf16 (16B)
    if (n >= N_NODES) return;

    const u16x8* xs8 = (const u16x8*)xhs;
    float dn = dinv[n];
    u16x8 sv = xs8[n * 16 + lane];                 // self term = xhs[n]
    float acc[8];
    #pragma unroll
    for (int j = 0; j < 8; ++j) acc[j] = bf16tof(sv[j]);

    int beg = row_ptr[n];
    int end = row_ptr[n + 1];
    int e = beg;
    for (; e + 3 < end; e += 4) {                  // 4 independent 16B gathers in flight
        int2 p0 = pairs[e];
        int2 p1 = pairs[e + 1];
        int2 p2 = pairs[e + 2];
        int2 p3 = pairs[e + 3];
        float w0 = __int_as_float(p0.y);
        float w1 = __int_as_float(p1.y);
        float w2 = __int_as_float(p2.y);
        float w3 = __int_as_float(p3.y);
        u16x8 v0 = xs8[p0.x * 16 + lane];
        u16x8 v1 = xs8[p1.x * 16 + lane];
        u16x8 v2 = xs8[p2.x * 16 + lane];
        u16x8 v3 = xs8[p3.x * 16 + lane];
        #pragma unroll
        for (int j = 0; j < 8; ++j) acc[j] += w0 * bf16tof(v0[j]);
        #pragma unroll
        for (int j = 0; j < 8; ++j) acc[j] += w1 * bf16tof(v1[j]);
        #pragma unroll
        for (int j = 0; j < 8; ++j) acc[j] += w2 * bf16tof(v2[j]);
        #pragma unroll
        for (int j = 0; j < 8; ++j) acc[j] += w3 * bf16tof(v3[j]);
    }
    for (; e < end; ++e) {
        int2 p = pairs[e];
        float w = __int_as_float(p.y);
        u16x8 v = xs8[p.x * 16 + lane];
        #pragma unroll
        for (int j = 0; j < 8; ++j) acc[j] += w * bf16tof(v[j]);
    }
    uint4 r;
    r.x = bf16rn(dn * acc[0]) | (bf16rn(dn * acc[1]) << 16);
    r.y = bf16rn(dn * acc[2]) | (bf16rn(dn * acc[3]) << 16);
    r.z = bf16rn(dn * acc[4]) | (bf16rn(dn * acc[5]) << 16);
    r.w = bf16rn(dn * acc[6]) | (bf16rn(dn * acc[7]) << 16);
    ((uint4*)axh)[n * 16 + lane] = r;
}

// ---------------- MFMA MLP: out = relu(axh@W1 + b1) @ W2 + b2 ----------------
// 4 waves/block, 16 rows/wave. 16x16x32 bf16 MFMA, fp32 accum.
// C/D layout (m89-verified): col = lane&15, row = (lane>>4)*4 + reg.

__global__ __launch_bounds__(256) void k_mlp(
        const unsigned short* __restrict__ axh,   // [N][128] bf16
        const unsigned short* __restrict__ w1t,   // [128][128] bf16, w1t[n][k]
        const float* __restrict__ b1,
        const unsigned short* __restrict__ w2t,   // [64][128] bf16, w2t[n][k]
        const float* __restrict__ b2,
        float* __restrict__ out) {
    __shared__ unsigned short hbuf[4][16][128];   // per-wave h tile, XOR-swizzled

    const int wid  = threadIdx.x >> 6;
    const int lane = threadIdx.x & 63;
    const int r = lane & 15;
    const int g = lane >> 4;

    const int row0 = (blockIdx.x * 4 + wid) * 16;
    const bool valid = (row0 + 16 <= N_NODES);    // N%16==0: waves all-or-nothing
    const int row0s = valid ? row0 : 0;

    bf16x8 a[4];
    const unsigned short* arow = axh + (size_t)(row0s + r) * HID + g * 8;
    #pragma unroll
    for (int kt = 0; kt < 4; ++kt)
        a[kt] = *(const bf16x8*)(arow + kt * 32);

    const int swr = (r & 7) << 3;

    #pragma unroll
    for (int nt = 0; nt < 8; ++nt) {
        f32x4 acc = {0.f, 0.f, 0.f, 0.f};
        const unsigned short* bcol = w1t + (nt * 16 + r) * HID + g * 8;
        #pragma unroll
        for (int kt = 0; kt < 4; ++kt) {
            bf16x8 b = *(const bf16x8*)(bcol + kt * 32);
            acc = __builtin_amdgcn_mfma_f32_16x16x32_bf16(a[kt], b, acc, 0, 0, 0);
        }
        float bias = b1[nt * 16 + r];
        #pragma unroll
        for (int q = 0; q < 4; ++q) {
            int row = g * 4 + q;
            float v = fmaxf(acc[q] + bias, 0.0f);
            hbuf[wid][row][(nt * 16 + r) ^ ((row & 7) << 3)] = (unsigned short)bf16rn(v);
        }
    }
    __syncthreads();   // all waves reach this (no early returns)

    bf16x8 a2[4];
    #pragma unroll
    for (int kt = 0; kt < 4; ++kt)
        a2[kt] = *(const bf16x8*)(&hbuf[wid][r][(kt * 32 + g * 8) ^ swr]);

    #pragma unroll
    for (int nt = 0; nt < 4; ++nt) {
        f32x4 acc = {0.f, 0.f, 0.f, 0.f};
        const unsigned short* bcol = w2t + (nt * 16 + r) * HID + g * 8;
        #pragma unroll
        for (int kt = 0; kt < 4; ++kt) {
            bf16x8 b = *(const bf16x8*)(bcol + kt * 32);
            acc = __builtin_amdgcn_mfma_f32_16x16x32_bf16(a2[kt], b, acc, 0, 0, 0);
        }
        if (valid) {
            float bias = b2[nt * 16 + r];
            #pragma unroll
            for (int q = 0; q < 4; ++q)
                out[(size_t)(row0 + g * 4 + q) * F_OUT + nt * 16 + r] = acc[q] + bias;
        }
    }
}

// ---------------- launch ----------------

extern "C" void kernel_launch(void* const* d_in, const int* in_sizes, int n_in,
                              void* d_out, int out_size, void* d_ws, size_t ws_size,
                              hipStream_t stream) {
    const float* x  = (const float*)d_in[0];
    const int*   ei = (const int*)d_in[1];
    const float* ew = (const float*)d_in[2];
    const float* W1 = (const float*)d_in[3];
    const float* b1 = (const float*)d_in[4];
    const float* W2 = (const float*)d_in[5];
    const float* b2 = (const float*)d_in[6];
    float* out = (float*)d_out;

    const int* src = ei;
    const int* dst = ei + N_EDGES;

    // workspace layout — explicit 16B-aligned carve-out.
    // NOTE: axh aliases spw (spw dead after k_csr; axh written after, in k_gather).
    char* base = (char*)d_ws;
    auto alloc16 = [&](size_t bytes) { char* p = base; base += (bytes + 15) & ~(size_t)15; return p; };

    float*          dinv    = (float*)         alloc16(N_NODES * 4);
    unsigned short* xhs     = (unsigned short*)alloc16((size_t)N_NODES * F_IN * 2);
    int*            row_ptr = (int*)           alloc16((N_NODES + 1) * 4);
    int*            ghist   = (int*)           alloc16(GHN * 4);
    int*            ghs     = (int*)           alloc16(GHN * 4);
    int2*           pairs   = (int2*)          alloc16((size_t)N_EDGES * 8);
    char*           big     =                  alloc16((size_t)N_NODES * HID * 2);  // 25.6MB >= E*8
    unsigned short* w1t     = (unsigned short*)alloc16(HID * F_IN * 2);
    unsigned short* w2t     = (unsigned short*)alloc16(F_OUT * HID * 2);

    int2*           spw     = (int2*)big;              // live: k_bscatter -> k_csr
    unsigned short* axh     = (unsigned short*)big;    // live: k_gather -> k_mlp

    k_pre0<<<WC_BLKS + NCHB, 256, 0, stream>>>(W1, W2, w1t, w2t, dst, ghist);
    k_scan<<<SCAN_BLKS, 256, 0, stream>>>(ghist, ghs);
    k_bscatter<<<NCHB, 256, 0, stream>>>(src, dst, ew, ghs, spw);
    k_csr<<<NBUCK, 512, 0, stream>>>(spw, ghs, x, row_ptr, dinv, pairs, xhs);
    k_gather<<<(N_NODES * 16 + 255) / 256, 256, 0, stream>>>(pairs, row_ptr, dinv, xhs, axh);
    k_mlp<<<(N_NODES / 16 + 3) / 4, 256, 0, stream>>>(axh, w1t, b1, w2t, b2, out);
}

// Round 13
// 205.808 us; speedup vs baseline: 1.0200x; 1.0014x over previous
//
#include <hip/hip_runtime.h>

#define N_NODES 100000
#define N_EDGES 1600000
#define F_IN    128
#define HID     128
#define F_OUT   64

#define NBUCK   196        // buckets of 512 nodes: dst>>9
#define NCHB    256        // chunk blocks for bucket hist/scatter
#define CHUNK_E (N_EDGES / NCHB)   // 6250 exactly
#define GHN     (NBUCK * NCHB)     // 50176 ghist entries
#define SCAN_BLKS (GHN / 256)      // 196 (exact)

#define WC_BLKS ((HID * F_IN + F_OUT * HID + 255) / 256)  // 96
#define XHS_BLKS ((N_NODES * 16 + 255) / 256)             // 6250

typedef __attribute__((ext_vector_type(8))) short bf16x8;
typedef __attribute__((ext_vector_type(8))) unsigned short u16x8;
typedef __attribute__((ext_vector_type(4))) float f32x4;

// ---------------- bf16 helpers ----------------

__device__ __forceinline__ unsigned int bf16rn(float f) {
    unsigned int u = __float_as_uint(f);
    return (u + 0x7fffu + ((u >> 16) & 1u)) >> 16;
}
__device__ __forceinline__ float bf16tof(unsigned short h) {
    return __uint_as_float(((unsigned int)h) << 16);
}

// ---------------- pre: weight transpose + bucket histogram ----------------

__global__ __launch_bounds__(256) void k_pre0(
        const float* __restrict__ W1, const float* __restrict__ W2,
        unsigned short* __restrict__ w1t, unsigned short* __restrict__ w2t,
        const int* __restrict__ dst, int* __restrict__ ghist) {
    __shared__ int bins[NBUCK];
    const int blk = blockIdx.x;
    const int t = threadIdx.x;
    if (blk < WC_BLKS) {
        int i = blk * 256 + t;
        if (i < HID * F_IN) {
            int n = i >> 7, k = i & 127;
            w1t[i] = (unsigned short)bf16rn(W1[k * HID + n]);
        }
        int j = i - HID * F_IN;
        if (j >= 0 && j < F_OUT * HID) {
            int n = j >> 7, k = j & 127;
            w2t[j] = (unsigned short)bf16rn(W2[k * F_OUT + n]);
        }
    } else {
        int cb = blk - WC_BLKS;
        for (int j = t; j < NBUCK; j += 256) bins[j] = 0;
        __syncthreads();
        const int base = cb * CHUNK_E;
        for (int i = t; i < CHUNK_E; i += 256)
            atomicAdd(&bins[dst[base + i] >> 9], 1);
        __syncthreads();
        for (int j = t; j < NBUCK; j += 256)
            ghist[j * NCHB + cb] = bins[j];       // bucket-major
    }
}

// ---------------- single-kernel exclusive scan: ghist -> ghs ----------------

__global__ __launch_bounds__(256) void k_scan(const int* __restrict__ ghist,
                                              int* __restrict__ ghs) {
    __shared__ int red[256];
    const int t = threadIdx.x;
    const int b = blockIdx.x;

    int s = 0;
    for (int i = t; i < b * 256; i += 256) s += ghist[i];
    red[t] = s;
    __syncthreads();
    for (int off = 128; off > 0; off >>= 1) {
        if (t < off) red[t] += red[t + off];
        __syncthreads();
    }
    const int base = red[0];
    __syncthreads();

    int v = ghist[b * 256 + t];
    red[t] = v;
    __syncthreads();
    for (int off = 1; off < 256; off <<= 1) {
        int u = (t >= off) ? red[t - off] : 0;
        __syncthreads();
        red[t] += u;
        __syncthreads();
    }
    ghs[b * 256 + t] = base + red[t] - v;         // exclusive
}

// ---------------- bucket scatter: LDS cursors, dlocal packed into bits 17..25 ----------------

__global__ __launch_bounds__(256) void k_bscatter(const int* __restrict__ src,
                                                  const int* __restrict__ dst,
                                                  const float* __restrict__ w,
                                                  const int* __restrict__ ghs,  // scanned
                                                  int2* __restrict__ spw) {
    __shared__ int cur[NBUCK];
    const int t = threadIdx.x;
    const int blk = blockIdx.x;
    for (int j = t; j < NBUCK; j += 256) cur[j] = ghs[j * NCHB + blk];
    __syncthreads();
    const int base = blk * CHUNK_E;
    for (int i = t; i < CHUNK_E; i += 256) {
        int e = base + i;
        int d = dst[e];
        int b = d >> 9;
        int pos = atomicAdd(&cur[b], 1);
        int2 p;
        p.x = src[e] | ((d & 511) << 17);     // src < 2^17
        p.y = __float_as_int(w[e]);
        spw[pos] = p;
    }
}

// ---------------- csr1: per-bucket degree + row_ptr + dinv (196 blocks) ----------------

__global__ __launch_bounds__(512) void k_csr1(const int2* __restrict__ spw,
                                              const int* __restrict__ ghs,   // scanned
                                              int* __restrict__ row_ptr,
                                              float* __restrict__ dinv) {
    __shared__ int   scnt[512];
    __shared__ float swsum[512];
    __shared__ int   sexcl[512];
    const int t = threadIdx.x;
    const int b = blockIdx.x;
    const int bstart = ghs[b * NCHB];
    const int bend   = (b == NBUCK - 1) ? N_EDGES : ghs[(b + 1) * NCHB];
    const int ne = bend - bstart;

    scnt[t] = 0; swsum[t] = 0.0f;
    __syncthreads();
    for (int i = t; i < ne; i += 512) {
        int2 pe = spw[bstart + i];
        int dl = pe.x >> 17;
        atomicAdd(&scnt[dl], 1);
        atomicAdd(&swsum[dl], __int_as_float(pe.y));
    }
    __syncthreads();

    sexcl[t] = scnt[t];
    __syncthreads();
    for (int off = 1; off < 512; off <<= 1) {
        int u = (t >= off) ? sexcl[t - off] : 0;
        __syncthreads();
        sexcl[t] += u;
        __syncthreads();
    }
    int excl = sexcl[t] - scnt[t];

    const int node = b * 512 + t;
    if (node < N_NODES) {
        row_ptr[node] = bstart + excl;
        dinv[node] = rsqrtf(1.0f + swsum[t]);
    }
    if (b == NBUCK - 1 && t == 0) row_ptr[N_NODES] = N_EDGES;
}

// ---------------- fin: pairs scatter (blocks 0..195) + xhs streaming (rest) ----------------
// Scatter cursors seeded directly from row_ptr. xhs at full-GPU occupancy.

__global__ __launch_bounds__(256) void k_fin(const int2* __restrict__ spw,
                                             const int* __restrict__ ghs,
                                             const int* __restrict__ row_ptr,
                                             const float* __restrict__ dinv,
                                             const float* __restrict__ x,
                                             int2* __restrict__ pairs,
                                             unsigned short* __restrict__ xhs) {
    const int blk = blockIdx.x;
    const int t = threadIdx.x;
    if (blk < NBUCK) {
        __shared__ int cur[512];
        const int b = blk;
        const int bstart = ghs[b * NCHB];
        const int bend   = (b == NBUCK - 1) ? N_EDGES : ghs[(b + 1) * NCHB];
        const int ne = bend - bstart;
        const int nbase = b * 512;
        for (int i = t; i < 512; i += 256) {
            int node = nbase + i;
            cur[i] = (node < N_NODES) ? row_ptr[node] : 0;
        }
        __syncthreads();
        for (int i = t; i < ne; i += 256) {
            int2 pe = spw[bstart + i];          // L2-hot from bscatter
            int dl = pe.x >> 17;
            int pos = atomicAdd(&cur[dl], 1);
            int2 q;
            q.x = pe.x & 0x1FFFF;
            q.y = pe.y;
            pairs[pos] = q;
        }
    } else {
        int i = (blk - NBUCK) * 256 + t;        // over N*16, 8 floats each
        if (i < N_NODES * 16) {
            float dn = dinv[i >> 4];
            float4 a = ((const float4*)x)[2 * i];
            float4 b = ((const float4*)x)[2 * i + 1];
            uint4 r;
            r.x = bf16rn(dn * a.x) | (bf16rn(dn * a.y) << 16);
            r.y = bf16rn(dn * a.z) | (bf16rn(dn * a.w) << 16);
            r.z = bf16rn(dn * b.x) | (bf16rn(dn * b.y) << 16);
            r.w = bf16rn(dn * b.z) | (bf16rn(dn * b.w) << 16);
            ((uint4*)xhs)[i] = r;
        }
    }
}

// ---------------- gather-aggregate: 16 lanes/node, 16B loads ----------------
// axh[n] = bf16( dn * (xhs[n] + sum_e w*xhs[src]) ) ; 2 VMEM/edge, dwordx4 width.

__global__ __launch_bounds__(256) void k_gather(const int2* __restrict__ pairs,
                                                const int* __restrict__ row_ptr,
                                                const float* __restrict__ dinv,
                                                const unsigned short* __restrict__ xhs,
                                                unsigned short* __restrict__ axh) {
    int t = blockIdx.x * 256 + threadIdx.x;
    int n = t >> 4;                                // 16 lanes per node
    int lane = t & 15;                             // handles 8 bf16 (16B)
    if (n >= N_NODES) return;

    const u16x8* xs8 = (const u16x8*)xhs;
    float dn = dinv[n];
    u16x8 sv = xs8[n * 16 + lane];                 // self term = xhs[n]
    float acc[8];
    #pragma unroll
    for (int j = 0; j < 8; ++j) acc[j] = bf16tof(sv[j]);

    int beg = row_ptr[n];
    int end = row_ptr[n + 1];
    int e = beg;
    for (; e + 3 < end; e += 4) {                  // 4 independent 16B gathers in flight
        int2 p0 = pairs[e];
        int2 p1 = pairs[e + 1];
        int2 p2 = pairs[e + 2];
        int2 p3 = pairs[e + 3];
        float w0 = __int_as_float(p0.y);
        float w1 = __int_as_float(p1.y);
        float w2 = __int_as_float(p2.y);
        float w3 = __int_as_float(p3.y);
        u16x8 v0 = xs8[p0.x * 16 + lane];
        u16x8 v1 = xs8[p1.x * 16 + lane];
        u16x8 v2 = xs8[p2.x * 16 + lane];
        u16x8 v3 = xs8[p3.x * 16 + lane];
        #pragma unroll
        for (int j = 0; j < 8; ++j) acc[j] += w0 * bf16tof(v0[j]);
        #pragma unroll
        for (int j = 0; j < 8; ++j) acc[j] += w1 * bf16tof(v1[j]);
        #pragma unroll
        for (int j = 0; j < 8; ++j) acc[j] += w2 * bf16tof(v2[j]);
        #pragma unroll
        for (int j = 0; j < 8; ++j) acc[j] += w3 * bf16tof(v3[j]);
    }
    for (; e < end; ++e) {
        int2 p = pairs[e];
        float w = __int_as_float(p.y);
        u16x8 v = xs8[p.x * 16 + lane];
        #pragma unroll
        for (int j = 0; j < 8; ++j) acc[j] += w * bf16tof(v[j]);
    }
    uint4 r;
    r.x = bf16rn(dn * acc[0]) | (bf16rn(dn * acc[1]) << 16);
    r.y = bf16rn(dn * acc[2]) | (bf16rn(dn * acc[3]) << 16);
    r.z = bf16rn(dn * acc[4]) | (bf16rn(dn * acc[5]) << 16);
    r.w = bf16rn(dn * acc[6]) | (bf16rn(dn * acc[7]) << 16);
    ((uint4*)axh)[n * 16 + lane] = r;
}

// ---------------- MFMA MLP: out = relu(axh@W1 + b1) @ W2 + b2 ----------------
// 4 waves/block, 16 rows/wave. 16x16x32 bf16 MFMA, fp32 accum.
// C/D layout (m89-verified): col = lane&15, row = (lane>>4)*4 + reg.

__global__ __launch_bounds__(256) void k_mlp(
        const unsigned short* __restrict__ axh,   // [N][128] bf16
        const unsigned short* __restrict__ w1t,   // [128][128] bf16, w1t[n][k]
        const float* __restrict__ b1,
        const unsigned short* __restrict__ w2t,   // [64][128] bf16, w2t[n][k]
        const float* __restrict__ b2,
        float* __restrict__ out) {
    __shared__ unsigned short hbuf[4][16][128];   // per-wave h tile, XOR-swizzled

    const int wid  = threadIdx.x >> 6;
    const int lane = threadIdx.x & 63;
    const int r = lane & 15;
    const int g = lane >> 4;

    const int row0 = (blockIdx.x * 4 + wid) * 16;
    const bool valid = (row0 + 16 <= N_NODES);    // N%16==0: waves all-or-nothing
    const int row0s = valid ? row0 : 0;

    bf16x8 a[4];
    const unsigned short* arow = axh + (size_t)(row0s + r) * HID + g * 8;
    #pragma unroll
    for (int kt = 0; kt < 4; ++kt)
        a[kt] = *(const bf16x8*)(arow + kt * 32);

    const int swr = (r & 7) << 3;

    #pragma unroll
    for (int nt = 0; nt < 8; ++nt) {
        f32x4 acc = {0.f, 0.f, 0.f, 0.f};
        const unsigned short* bcol = w1t + (nt * 16 + r) * HID + g * 8;
        #pragma unroll
        for (int kt = 0; kt < 4; ++kt) {
            bf16x8 b = *(const bf16x8*)(bcol + kt * 32);
            acc = __builtin_amdgcn_mfma_f32_16x16x32_bf16(a[kt], b, acc, 0, 0, 0);
        }
        float bias = b1[nt * 16 + r];
        #pragma unroll
        for (int q = 0; q < 4; ++q) {
            int row = g * 4 + q;
            float v = fmaxf(acc[q] + bias, 0.0f);
            hbuf[wid][row][(nt * 16 + r) ^ ((row & 7) << 3)] = (unsigned short)bf16rn(v);
        }
    }
    __syncthreads();   // all waves reach this (no early returns)

    bf16x8 a2[4];
    #pragma unroll
    for (int kt = 0; kt < 4; ++kt)
        a2[kt] = *(const bf16x8*)(&hbuf[wid][r][(kt * 32 + g * 8) ^ swr]);

    #pragma unroll
    for (int nt = 0; nt < 4; ++nt) {
        f32x4 acc = {0.f, 0.f, 0.f, 0.f};
        const unsigned short* bcol = w2t + (nt * 16 + r) * HID + g * 8;
        #pragma unroll
        for (int kt = 0; kt < 4; ++kt) {
            bf16x8 b = *(const bf16x8*)(bcol + kt * 32);
            acc = __builtin_amdgcn_mfma_f32_16x16x32_bf16(a2[kt], b, acc, 0, 0, 0);
        }
        if (valid) {
            float bias = b2[nt * 16 + r];
            #pragma unroll
            for (int q = 0; q < 4; ++q)
                out[(size_t)(row0 + g * 4 + q) * F_OUT + nt * 16 + r] = acc[q] + bias;
        }
    }
}

// ---------------- launch ----------------

extern "C" void kernel_launch(void* const* d_in, const int* in_sizes, int n_in,
                              void* d_out, int out_size, void* d_ws, size_t ws_size,
                              hipStream_t stream) {
    const float* x  = (const float*)d_in[0];
    const int*   ei = (const int*)d_in[1];
    const float* ew = (const float*)d_in[2];
    const float* W1 = (const float*)d_in[3];
    const float* b1 = (const float*)d_in[4];
    const float* W2 = (const float*)d_in[5];
    const float* b2 = (const float*)d_in[6];
    float* out = (float*)d_out;

    const int* src = ei;
    const int* dst = ei + N_EDGES;

    // workspace layout — explicit 16B-aligned carve-out.
    // NOTE: axh aliases spw (spw dead after k_fin; axh written after, in k_gather).
    char* base = (char*)d_ws;
    auto alloc16 = [&](size_t bytes) { char* p = base; base += (bytes + 15) & ~(size_t)15; return p; };

    float*          dinv    = (float*)         alloc16(N_NODES * 4);
    unsigned short* xhs     = (unsigned short*)alloc16((size_t)N_NODES * F_IN * 2);
    int*            row_ptr = (int*)           alloc16((N_NODES + 1) * 4);
    int*            ghist   = (int*)           alloc16(GHN * 4);
    int*            ghs     = (int*)           alloc16(GHN * 4);
    int2*           pairs   = (int2*)          alloc16((size_t)N_EDGES * 8);
    char*           big     =                  alloc16((size_t)N_NODES * HID * 2);  // 25.6MB >= E*8
    unsigned short* w1t     = (unsigned short*)alloc16(HID * F_IN * 2);
    unsigned short* w2t     = (unsigned short*)alloc16(F_OUT * HID * 2);

    int2*           spw     = (int2*)big;              // live: k_bscatter -> k_fin
    unsigned short* axh     = (unsigned short*)big;    // live: k_gather -> k_mlp

    k_pre0<<<WC_BLKS + NCHB, 256, 0, stream>>>(W1, W2, w1t, w2t, dst, ghist);
    k_scan<<<SCAN_BLKS, 256, 0, stream>>>(ghist, ghs);
    k_bscatter<<<NCHB, 256, 0, stream>>>(src, dst, ew, ghs, spw);
    k_csr1<<<NBUCK, 512, 0, stream>>>(spw, ghs, row_ptr, dinv);
    k_fin<<<NBUCK + XHS_BLKS, 256, 0, stream>>>(spw, ghs, row_ptr, dinv, x, pairs, xhs);
    k_gather<<<(N_NODES * 16 + 255) / 256, 256, 0, stream>>>(pairs, row_ptr, dinv, xhs, axh);
    k_mlp<<<(N_NODES / 16 + 3) / 4, 256, 0, stream>>>(axh, w1t, b1, w2t, b2, out);
}

// Round 14
// 157.504 us; speedup vs baseline: 1.3328x; 1.3067x over previous
//
#include <hip/hip_runtime.h>

#define N_NODES 100000
#define N_EDGES 1600000
#define F_IN    128
#define HID     128
#define F_OUT   64

#define NBUCK   196        // buckets of 512 nodes: dst>>9
#define NCHB    256        // chunk blocks for bucket hist/scatter
#define CHUNK_E (N_EDGES / NCHB)   // 6250 exactly
#define GHN     (NBUCK * NCHB)     // 50176 ghist entries

#define XB_BLKS (N_NODES * 16 / 256)                  // 6250 (exact)
#define WC_BLKS ((HID * F_IN + F_OUT * HID + 255) / 256)  // 96

typedef __attribute__((ext_vector_type(8))) short bf16x8;
typedef __attribute__((ext_vector_type(8))) unsigned short u16x8;
typedef __attribute__((ext_vector_type(4))) float f32x4;

// ---------------- bf16 helpers ----------------

__device__ __forceinline__ unsigned int bf16rn(float f) {
    unsigned int u = __float_as_uint(f);
    return (u + 0x7fffu + ((u >> 16) & 1u)) >> 16;
}
__device__ __forceinline__ float bf16tof(unsigned short h) {
    return __uint_as_float(((unsigned int)h) << 16);
}

// ---------------- pre: xh convert + weight transpose + bucket histogram ----------------

__global__ __launch_bounds__(256) void k_pre(
        const float* __restrict__ x, unsigned short* __restrict__ xh,
        const float* __restrict__ W1, const float* __restrict__ W2,
        unsigned short* __restrict__ w1t, unsigned short* __restrict__ w2t,
        const int* __restrict__ dst, int* __restrict__ ghist) {
    __shared__ int bins[NBUCK];
    const int blk = blockIdx.x;
    const int t = threadIdx.x;
    if (blk < XB_BLKS) {
        int i = blk * 256 + t;
        float4 a = ((const float4*)x)[2 * i];
        float4 b = ((const float4*)x)[2 * i + 1];
        uint4 r;
        r.x = bf16rn(a.x) | (bf16rn(a.y) << 16);
        r.y = bf16rn(a.z) | (bf16rn(a.w) << 16);
        r.z = bf16rn(b.x) | (bf16rn(b.y) << 16);
        r.w = bf16rn(b.z) | (bf16rn(b.w) << 16);
        ((uint4*)xh)[i] = r;
    } else if (blk < XB_BLKS + WC_BLKS) {
        int i = (blk - XB_BLKS) * 256 + t;
        if (i < HID * F_IN) {
            int n = i >> 7, k = i & 127;
            w1t[i] = (unsigned short)bf16rn(W1[k * HID + n]);
        }
        int j = i - HID * F_IN;
        if (j >= 0 && j < F_OUT * HID) {
            int n = j >> 7, k = j & 127;
            w2t[j] = (unsigned short)bf16rn(W2[k * F_OUT + n]);
        }
    } else {
        int cb = blk - XB_BLKS - WC_BLKS;
        for (int j = t; j < NBUCK; j += 256) bins[j] = 0;
        __syncthreads();
        const int base = cb * CHUNK_E;
        for (int i = t; i < CHUNK_E; i += 256)
            atomicAdd(&bins[dst[base + i] >> 9], 1);
        __syncthreads();
        for (int j = t; j < NBUCK; j += 256)
            ghist[j * NCHB + cb] = bins[j];       // bucket-major
    }
}

// ---------------- hierarchical exclusive scan (3 kernels, R8-proven) ----------------

__global__ void k_scan_part(const int* __restrict__ data, int* __restrict__ part, int n) {
    int i = blockIdx.x * 256 + threadIdx.x;
    int v = (i < n) ? data[i] : 0;
    #pragma unroll
    for (int off = 32; off > 0; off >>= 1) v += __shfl_down(v, off, 64);
    __shared__ int ws[4];
    if ((threadIdx.x & 63) == 0) ws[threadIdx.x >> 6] = v;
    __syncthreads();
    if (threadIdx.x == 0) part[blockIdx.x] = ws[0] + ws[1] + ws[2] + ws[3];
}

__global__ __launch_bounds__(512) void k_scan_top(int* __restrict__ part, int nparts) {
    __shared__ int s[512];
    int t = threadIdx.x;
    int v = (t < nparts) ? part[t] : 0;
    s[t] = v;
    __syncthreads();
    for (int off = 1; off < 512; off <<= 1) {
        int u = (t >= off) ? s[t - off] : 0;
        __syncthreads();
        s[t] += u;
        __syncthreads();
    }
    if (t < nparts) part[t] = s[t] - v;           // exclusive
}

__global__ void k_scan_down(int* __restrict__ data, const int* __restrict__ part, int n) {
    __shared__ int s[256];
    int t = threadIdx.x;
    int i = blockIdx.x * 256 + t;
    int v = (i < n) ? data[i] : 0;
    s[t] = v;
    __syncthreads();
    for (int off = 1; off < 256; off <<= 1) {
        int u = (t >= off) ? s[t - off] : 0;
        __syncthreads();
        s[t] += u;
        __syncthreads();
    }
    if (i < n) data[i] = part[blockIdx.x] + s[t] - v;   // exclusive, in place
}

// ---------------- bucket scatter: LDS cursors, dlocal packed into bits 17..25 ----------------

__global__ __launch_bounds__(256) void k_bscatter(const int* __restrict__ src,
                                                  const int* __restrict__ dst,
                                                  const float* __restrict__ w,
                                                  const int* __restrict__ ghist,  // scanned
                                                  int2* __restrict__ spw) {
    __shared__ int cur[NBUCK];
    const int t = threadIdx.x;
    const int blk = blockIdx.x;
    for (int j = t; j < NBUCK; j += 256) cur[j] = ghist[j * NCHB + blk];
    __syncthreads();
    const int base = blk * CHUNK_E;
    for (int i = t; i < CHUNK_E; i += 256) {
        int e = base + i;
        int d = dst[e];
        int b = d >> 9;
        int pos = atomicAdd(&cur[b], 1);
        int2 p;
        p.x = src[e] | ((d & 511) << 17);     // src < 2^17
        p.y = __float_as_int(w[e]);
        spw[pos] = p;
    }
}

// ---------------- per-bucket CSR finalize: row_ptr, dinv, pairs ----------------

__global__ __launch_bounds__(512) void k_csr(const int2* __restrict__ spw,
                                             const int* __restrict__ ghist,   // scanned
                                             int* __restrict__ row_ptr,
                                             float* __restrict__ dinv,
                                             int2* __restrict__ pairs) {
    __shared__ int   scnt[512];
    __shared__ float swsum[512];
    __shared__ int   sexcl[512];
    const int t = threadIdx.x;
    const int b = blockIdx.x;
    const int bstart = ghist[b * NCHB];
    const int bend   = (b == NBUCK - 1) ? N_EDGES : ghist[(b + 1) * NCHB];
    const int ne = bend - bstart;

    scnt[t] = 0; swsum[t] = 0.0f;
    __syncthreads();
    for (int i = t; i < ne; i += 512) {
        int2 pe = spw[bstart + i];
        int dl = pe.x >> 17;
        atomicAdd(&scnt[dl], 1);
        atomicAdd(&swsum[dl], __int_as_float(pe.y));
    }
    __syncthreads();

    sexcl[t] = scnt[t];
    __syncthreads();
    for (int off = 1; off < 512; off <<= 1) {
        int u = (t >= off) ? sexcl[t - off] : 0;
        __syncthreads();
        sexcl[t] += u;
        __syncthreads();
    }
    int excl = sexcl[t] - scnt[t];

    int node = b * 512 + t;
    if (node < N_NODES) {
        row_ptr[node] = bstart + excl;
        dinv[node] = rsqrtf(1.0f + swsum[t]);
    }
    if (b == NBUCK - 1 && t == 0) row_ptr[N_NODES] = N_EDGES;

    sexcl[t] = excl;
    __syncthreads();
    scnt[t] = 0;
    __syncthreads();

    for (int i = t; i < ne; i += 512) {
        int2 pe = spw[bstart + i];
        int dl = pe.x >> 17;
        int r = atomicAdd(&scnt[dl], 1);
        int2 q;
        q.x = pe.x & 0x1FFFF;
        q.y = pe.y;
        pairs[bstart + sexcl[dl] + r] = q;
    }
}

// ---------------- gather-aggregate: 16 lanes/node, 16B loads ----------------
// axh[n] = bf16( dn * ( dn*xh[n] + sum_e dinv[src]*w * xh[src] ) )

__global__ __launch_bounds__(256) void k_gather(const int2* __restrict__ pairs,
                                                const int* __restrict__ row_ptr,
                                                const float* __restrict__ dinv,
                                                const unsigned short* __restrict__ xh,
                                                unsigned short* __restrict__ axh) {
    int t = blockIdx.x * 256 + threadIdx.x;
    int n = t >> 4;                                // 16 lanes per node
    int lane = t & 15;                             // 8 bf16 (16B) per lane
    if (n >= N_NODES) return;

    const u16x8* xh8 = (const u16x8*)xh;
    float dn = dinv[n];
    u16x8 sv = xh8[n * 16 + lane];                 // self term
    float acc[8];
    #pragma unroll
    for (int j = 0; j < 8; ++j) acc[j] = dn * bf16tof(sv[j]);

    int beg = row_ptr[n];
    int end = row_ptr[n + 1];
    int e = beg;
    for (; e + 3 < end; e += 4) {                  // 4 independent 16B gathers in flight
        int2 p0 = pairs[e];
        int2 p1 = pairs[e + 1];
        int2 p2 = pairs[e + 2];
        int2 p3 = pairs[e + 3];
        float nw0 = dinv[p0.x] * __int_as_float(p0.y);
        float nw1 = dinv[p1.x] * __int_as_float(p1.y);
        float nw2 = dinv[p2.x] * __int_as_float(p2.y);
        float nw3 = dinv[p3.x] * __int_as_float(p3.y);
        u16x8 v0 = xh8[p0.x * 16 + lane];
        u16x8 v1 = xh8[p1.x * 16 + lane];
        u16x8 v2 = xh8[p2.x * 16 + lane];
        u16x8 v3 = xh8[p3.x * 16 + lane];
        #pragma unroll
        for (int j = 0; j < 8; ++j) acc[j] += nw0 * bf16tof(v0[j]);
        #pragma unroll
        for (int j = 0; j < 8; ++j) acc[j] += nw1 * bf16tof(v1[j]);
        #pragma unroll
        for (int j = 0; j < 8; ++j) acc[j] += nw2 * bf16tof(v2[j]);
        #pragma unroll
        for (int j = 0; j < 8; ++j) acc[j] += nw3 * bf16tof(v3[j]);
    }
    for (; e < end; ++e) {
        int2 p = pairs[e];
        float nw = dinv[p.x] * __int_as_float(p.y);
        u16x8 v = xh8[p.x * 16 + lane];
        #pragma unroll
        for (int j = 0; j < 8; ++j) acc[j] += nw * bf16tof(v[j]);
    }
    uint4 r;
    r.x = bf16rn(dn * acc[0]) | (bf16rn(dn * acc[1]) << 16);
    r.y = bf16rn(dn * acc[2]) | (bf16rn(dn * acc[3]) << 16);
    r.z = bf16rn(dn * acc[4]) | (bf16rn(dn * acc[5]) << 16);
    r.w = bf16rn(dn * acc[6]) | (bf16rn(dn * acc[7]) << 16);
    ((uint4*)axh)[n * 16 + lane] = r;
}

// ---------------- MFMA MLP: out = relu(axh@W1 + b1) @ W2 + b2 ----------------
// 64 rows/wave (4 row-tiles), 4 waves/block = 256 rows/block, 391 blocks.
// B-fragments (w1t/w2t from L2) loaded once per (nt,kt), REUSED across 4 row-tiles
// -> weight L2 traffic /4 vs old 16-row version. No __syncthreads: each wave
// only touches its own hbuf slice. Tail: per-row-tile validity (N%16==0).
// C/D layout (m89-verified): col = lane&15, row = (lane>>4)*4 + reg.

__global__ __launch_bounds__(256) void k_mlp(
        const unsigned short* __restrict__ axh,   // [N][128] bf16
        const unsigned short* __restrict__ w1t,   // [128][128] bf16, w1t[n][k]
        const float* __restrict__ b1,
        const unsigned short* __restrict__ w2t,   // [64][128] bf16, w2t[n][k]
        const float* __restrict__ b2,
        float* __restrict__ out) {
    __shared__ unsigned short hbuf[4][64][128];   // per-wave 64-row h tile (64 KB)

    const int wid  = threadIdx.x >> 6;
    const int lane = threadIdx.x & 63;
    const int r = lane & 15;
    const int g = lane >> 4;
    const int swr = (r & 7) << 3;

    const int row0 = (blockIdx.x * 4 + wid) * 64;

    bool vld[4];
    int rbase[4];
    #pragma unroll
    for (int rt = 0; rt < 4; ++rt) {
        vld[rt] = (row0 + rt * 16 + 16 <= N_NODES);
        rbase[rt] = vld[rt] ? (row0 + rt * 16) : 0;
    }

    // A fragments, layer 1: a1[rt][kt]
    bf16x8 a1[4][4];
    #pragma unroll
    for (int rt = 0; rt < 4; ++rt) {
        const unsigned short* arow = axh + (size_t)(rbase[rt] + r) * HID + g * 8;
        #pragma unroll
        for (int kt = 0; kt < 4; ++kt)
            a1[rt][kt] = *(const bf16x8*)(arow + kt * 32);
    }

    // ---- layer 1: h[64][128] ----
    #pragma unroll
    for (int nt = 0; nt < 8; ++nt) {
        bf16x8 b[4];
        const unsigned short* bcol = w1t + (nt * 16 + r) * HID + g * 8;
        #pragma unroll
        for (int kt = 0; kt < 4; ++kt)
            b[kt] = *(const bf16x8*)(bcol + kt * 32);
        float bias = b1[nt * 16 + r];
        #pragma unroll
        for (int rt = 0; rt < 4; ++rt) {
            f32x4 acc = {0.f, 0.f, 0.f, 0.f};
            #pragma unroll
            for (int kt = 0; kt < 4; ++kt)
                acc = __builtin_amdgcn_mfma_f32_16x16x32_bf16(a1[rt][kt], b[kt], acc, 0, 0, 0);
            #pragma unroll
            for (int q = 0; q < 4; ++q) {
                int row16 = g * 4 + q;
                float v = fmaxf(acc[q] + bias, 0.0f);
                hbuf[wid][rt * 16 + row16][(nt * 16 + r) ^ ((row16 & 7) << 3)] =
                    (unsigned short)bf16rn(v);
            }
        }
    }
    // no barrier: same-wave LDS RAW ordering handled by lgkmcnt

    // A fragments, layer 2 (from swizzled LDS)
    bf16x8 a2[4][4];
    #pragma unroll
    for (int rt = 0; rt < 4; ++rt)
        #pragma unroll
        for (int kt = 0; kt < 4; ++kt)
            a2[rt][kt] = *(const bf16x8*)(&hbuf[wid][rt * 16 + r][(kt * 32 + g * 8) ^ swr]);

    // ---- layer 2: out[64][64] ----
    #pragma unroll
    for (int nt = 0; nt < 4; ++nt) {
        bf16x8 b[4];
        const unsigned short* bcol = w2t + (nt * 16 + r) * HID + g * 8;
        #pragma unroll
        for (int kt = 0; kt < 4; ++kt)
            b[kt] = *(const bf16x8*)(bcol + kt * 32);
        float bias = b2[nt * 16 + r];
        #pragma unroll
        for (int rt = 0; rt < 4; ++rt) {
            f32x4 acc = {0.f, 0.f, 0.f, 0.f};
            #pragma unroll
            for (int kt = 0; kt < 4; ++kt)
                acc = __builtin_amdgcn_mfma_f32_16x16x32_bf16(a2[rt][kt], b[kt], acc, 0, 0, 0);
            if (vld[rt]) {
                #pragma unroll
                for (int q = 0; q < 4; ++q)
                    out[(size_t)(row0 + rt * 16 + g * 4 + q) * F_OUT + nt * 16 + r] =
                        acc[q] + bias;
            }
        }
    }
}

// ---------------- launch ----------------

extern "C" void kernel_launch(void* const* d_in, const int* in_sizes, int n_in,
                              void* d_out, int out_size, void* d_ws, size_t ws_size,
                              hipStream_t stream) {
    const float* x  = (const float*)d_in[0];
    const int*   ei = (const int*)d_in[1];
    const float* ew = (const float*)d_in[2];
    const float* W1 = (const float*)d_in[3];
    const float* b1 = (const float*)d_in[4];
    const float* W2 = (const float*)d_in[5];
    const float* b2 = (const float*)d_in[6];
    float* out = (float*)d_out;

    const int* src = ei;
    const int* dst = ei + N_EDGES;

    // workspace layout — explicit 16B-aligned carve-out.
    // NOTE: axh aliases spw (spw dead after k_csr; axh written after, in k_gather).
    char* base = (char*)d_ws;
    auto alloc16 = [&](size_t bytes) { char* p = base; base += (bytes + 15) & ~(size_t)15; return p; };

    float*          dinv    = (float*)         alloc16(N_NODES * 4);
    unsigned short* xh      = (unsigned short*)alloc16((size_t)N_NODES * F_IN * 2);
    int*            row_ptr = (int*)           alloc16((N_NODES + 1) * 4);
    int*            ghist   = (int*)           alloc16(GHN * 4);
    int*            part    = (int*)           alloc16(256 * 4);
    int2*           pairs   = (int2*)          alloc16((size_t)N_EDGES * 8);
    char*           big     =                  alloc16((size_t)N_NODES * HID * 2);  // 25.6MB >= E*8
    unsigned short* w1t     = (unsigned short*)alloc16(HID * F_IN * 2);
    unsigned short* w2t     = (unsigned short*)alloc16(F_OUT * HID * 2);

    int2*           spw     = (int2*)big;              // live: k_bscatter -> k_csr
    unsigned short* axh     = (unsigned short*)big;    // live: k_gather -> k_mlp

    const int GH_BLKS = (GHN + 255) / 256;   // 196

    k_pre<<<XB_BLKS + WC_BLKS + NCHB, 256, 0, stream>>>(x, xh, W1, W2, w1t, w2t, dst, ghist);
    k_scan_part<<<GH_BLKS, 256, 0, stream>>>(ghist, part, GHN);
    k_scan_top<<<1, 512, 0, stream>>>(part, GH_BLKS);
    k_scan_down<<<GH_BLKS, 256, 0, stream>>>(ghist, part, GHN);
    k_bscatter<<<NCHB, 256, 0, stream>>>(src, dst, ew, ghist, spw);
    k_csr<<<NBUCK, 512, 0, stream>>>(spw, ghist, row_ptr, dinv, pairs);
    k_gather<<<(N_NODES * 16 + 255) / 256, 256, 0, stream>>>(pairs, row_ptr, dinv, xh, axh);
    k_mlp<<<(N_NODES + 255) / 256, 256, 0, stream>>>(axh, w1t, b1, w2t, b2, out);
}